// Round 6
// baseline (104.141 us; speedup 1.0000x reference)
//
#include <hip/hip_runtime.h>
#include <math.h>

// StructureLoss: pred [16,2,512,512] f32, mask [16,512,512] f32 -> scalar f32
// loss = mean_b( wbce_b + wiou_b ), weit = 1 + 5*|boxavg31(m) - m|
//
// R11 = R10 kernel UNCHANGED, but the tile kernel is dispatched TWICE
// (idempotent: pure function of inputs, writes identical g_part values).
// This is a deliberate marginal-cost measurement: dur_us(R11) - dur_us(R10)
// = the true duration of one tile dispatch (L3-warm lower bound), which has
// never been directly visible (always below the top-5 profile cutoff of
// ~41.4 us held by the harness's unconditional 256 MiB workspace fills).
// Pre-committed read: delta <= 10 us -> tile near its ~10 us floor, fixed
// harness overhead ~72 us, declare roofline next round; delta >= 15 us ->
// attack phase serialization (3 blocks/CU via smaller tile) next round.
#define B_   16
#define H_   512
#define W_   512
#define HW_  (H_ * W_)
#define MU_  5.0f
#define KK_INV (1.0f / 961.0f)
#define TH   128
#define TW   64
#define NTHR 512
#define NROWS 158              // TH + 30
#define RSTRIDE 100            // raw row stride: 16B-aligned, 4 mod 32 banks
#define VSTRIDE 95             // vsum stride: odd -> scalar reads <=2-way
#define NQ 24                  // float4s staged per raw row (96 cols, 94 used)
#define NSTG (NROWS * NQ)      // 3792 staging tasks
#define NVTASK 376             // 4 row-groups(32) x 94 halo cols
#define NBLK 512               // 8 x 4 x 16

__device__ __align__(16) float g_part[NBLK * 4];

__global__ __launch_bounds__(NTHR, 4) void structure_loss_tile(
    const float* __restrict__ pred,     // [B,2,H,W]
    const float* __restrict__ mask)     // [B,H,W]
{
    __shared__ float smem[NROWS * RSTRIDE];   // 63,200 B; vsum aliased after P3
    __shared__ float wsum[8][4];

    const int tid = threadIdx.x;

    // ---- XCD-aware tile assignment (bijective: 512 = 8 XCDs x 64) ----
    const int bid = (blockIdx.z * gridDim.y + blockIdx.y) * gridDim.x + blockIdx.x;
    const int t   = (bid & 7) * 64 + (bid >> 3);
    const int tx  = t & 7;
    const int ty  = (t >> 3) & 3;
    const int b   = t >> 5;
    const int r0  = ty * TH;
    const int c0  = tx * TW;
    const int blk = t;                  // g_part layout: tile-index order

    const float* mb = mask + (size_t)b * HW_;
    const float* pb = pred + ((size_t)b * 2 + 1) * HW_;   // channel-1 logits

    // ---- Horizontal-phase coordinates: 16 output px per thread ----
    const int r   = tid >> 2;           // 0..127
    const int ch  = tid & 3;            // 0..3
    const int gr  = r0 + r;
    const int gcb = c0 + ch * 16;       // 64B-aligned

    // ---- P1a: pred prefetch (4 float4), issued with the stage loads ----
    const float4* p4 = (const float4*)(pb + gr * W_ + gcb);
    const float4 pq0 = p4[0], pq1 = p4[1], pq2 = p4[2], pq3 = p4[3];

    // ---- P1b: stage raw mask halo: 158 rows x 24 float4 = 3792 tasks ----
    {
        const int gyb = r0 - 15;
        const int gxb = c0 - 16;
        float4 vbuf[8];
        int    laddr[8];
        #pragma unroll
        for (int rnd = 0; rnd < 8; ++rnd) {
            const int task = tid + rnd * NTHR;
            float4 v = make_float4(0.f, 0.f, 0.f, 0.f);
            int la = -1;
            if (task < NSTG) {
                const int row = task / NQ;
                const int q   = task - row * NQ;
                const int gy  = gyb + row;
                const int gx  = gxb + q * 4;    // multiple of 4 -> f4-granular OOB
                if (((unsigned)gy < (unsigned)H_) & ((unsigned)gx < (unsigned)W_))
                    v = *(const float4*)(mb + gy * W_ + gx);
                la = row * RSTRIDE + q * 4;
            }
            vbuf[rnd] = v;
            laddr[rnd] = la;
        }
        #pragma unroll
        for (int rnd = 0; rnd < 8; ++rnd) {
            if (laddr[rnd] >= 0)
                *(float4*)(&smem[laddr[rnd]]) = vbuf[rnd];
        }
    }
    // keep pred values resident (don't let the loads sink past the barriers)
    asm volatile("" :: "v"(pq0.x), "v"(pq0.y), "v"(pq0.z), "v"(pq0.w),
                       "v"(pq1.x), "v"(pq1.y), "v"(pq1.z), "v"(pq1.w),
                       "v"(pq2.x), "v"(pq2.y), "v"(pq2.z), "v"(pq2.w),
                       "v"(pq3.x), "v"(pq3.y), "v"(pq3.z), "v"(pq3.w));
    __syncthreads();

    // ---- P2: mask row for elementwise (from staged raw) + vertical sums ----
    float mv[16];
    {
        const int mbase = (r + 15) * RSTRIDE + ch * 16 + 16;
        #pragma unroll
        for (int k = 0; k < 4; ++k) {
            const int kk = (k + ch) & 3;     // rotation: 2-way (free) with RSTRIDE=100
            const float4 tq = *(const float4*)(&smem[mbase + 4 * kk]);
            mv[kk*4+0] = tq.x; mv[kk*4+1] = tq.y; mv[kk*4+2] = tq.z; mv[kk*4+3] = tq.w;
        }
    }

    float vs[32];
    int rg = 0, cc = 0;
    if (tid < NVTASK) {
        rg = tid / 94;                       // 0..3
        cc = tid - rg * 94;                  // 0..93
        const float* col = &smem[(rg * 32) * RSTRIDE + cc + 1];
        float s = 0.0f;
        #pragma unroll
        for (int d = 0; d < 31; ++d)
            s += col[d * RSTRIDE];
        vs[0] = s;
        #pragma unroll
        for (int i = 1; i < 32; ++i) {
            s += col[(i + 30) * RSTRIDE] - col[(i - 1) * RSTRIDE];
            vs[i] = s;
        }
    }
    __syncthreads();

    // ---- P3: write vsum [128][95] over the raw region (alias, post-barrier) ----
    if (tid < NVTASK) {
        float* vout = &smem[(rg * 32) * VSTRIDE + cc];
        #pragma unroll
        for (int i = 0; i < 32; ++i)
            vout[i * VSTRIDE] = vs[i];
    }
    __syncthreads();

    // ---- P4: horizontal 31-tap slide fused with elementwise math ----
    const int base = r * VSTRIDE + ch * 16;
    float s = 0.0f;
    #pragma unroll
    for (int d = 0; d < 31; ++d)
        s += smem[base + d];

    float pv[16] = { pq0.x, pq0.y, pq0.z, pq0.w,  pq1.x, pq1.y, pq1.z, pq1.w,
                     pq2.x, pq2.y, pq2.z, pq2.w,  pq3.x, pq3.y, pq3.z, pq3.w };

    float s_w = 0.0f, s_wb = 0.0f, s_in = 0.0f, s_un = 0.0f;
    #pragma unroll
    for (int j = 0; j < 16; ++j) {
        const float avg = s * KK_INV;
        const float m = mv[j];
        const float p = pv[j];

        const float weit = 1.0f + MU_ * fabsf(avg - m);
        // e = exp(-|p|); bce = max(p,0) - p*m + log(1+e); sigmoid = (p>=0?1:e)/(1+e)
        const float e    = __expf(-fabsf(p));
        const float inv  = __builtin_amdgcn_rcpf(1.0f + e);
        const float bce  = fmaxf(p, 0.0f) - p * m + __logf(1.0f + e);
        const float ps   = (p >= 0.0f ? 1.0f : e) * inv;

        s_w  += weit;
        s_wb += weit * bce;
        s_in += ps * m * weit;
        s_un += (ps + m) * weit;

        if (j < 15)
            s += smem[base + 31 + j] - smem[base + j];
    }

    // ---- block reduction: wave shuffle -> LDS -> one store per component ----
    const int lane = tid & 63;
    const int wid  = tid >> 6;          // 0..7
    float vals[4] = { s_w, s_wb, s_in, s_un };
    #pragma unroll
    for (int q = 0; q < 4; ++q) {
        float v = vals[q];
        #pragma unroll
        for (int off = 32; off > 0; off >>= 1)
            v += __shfl_down(v, off);
        if (lane == 0) wsum[wid][q] = v;
    }
    __syncthreads();
    if (tid < 4) {
        float tot = 0.0f;
        #pragma unroll
        for (int w = 0; w < 8; ++w) tot += wsum[w][tid];
        g_part[blk * 4 + tid] = tot;    // unconditional write -> no memset needed
    }
}

__global__ void structure_loss_final(float* __restrict__ out)
{
    // 64 threads; 4 threads per batch (32 blocks/batch), 8 float4 each.
    const int t = threadIdx.x;
    const float4* p4 = (const float4*)g_part;    // one float4 per block
    float4 v = make_float4(0.f, 0.f, 0.f, 0.f);
    #pragma unroll
    for (int j = 0; j < 8; ++j) {
        const float4 q = p4[t * 8 + j];
        v.x += q.x; v.y += q.y; v.z += q.z; v.w += q.w;
    }
    #pragma unroll
    for (int off = 2; off > 0; off >>= 1) {
        v.x += __shfl_down(v.x, off);
        v.y += __shfl_down(v.y, off);
        v.z += __shfl_down(v.z, off);
        v.w += __shfl_down(v.w, off);
    }
    float loss = 0.0f;
    if ((t & 3) == 0) {
        const float sw = v.x, swb = v.y, inter = v.z, uni = v.w;
        loss = swb / sw + 1.0f - (inter + 1.0f) / (uni - inter + 1.0f);
    }
    #pragma unroll
    for (int off = 32; off >= 4; off >>= 1)
        loss += __shfl_down(loss, off);
    if (t == 0) out[0] = loss * (1.0f / (float)B_);
}

extern "C" void kernel_launch(void* const* d_in, const int* in_sizes, int n_in,
                              void* d_out, int out_size, void* d_ws, size_t ws_size,
                              hipStream_t stream) {
    const float* pred = (const float*)d_in[0];
    const float* mask = (const float*)d_in[1];
    float* out = (float*)d_out;
    (void)d_ws; (void)ws_size;          // workspace deliberately untouched

    dim3 grid(W_ / TW, H_ / TH, B_);    // 8 x 4 x 16 = 512 blocks
    // Marginal-cost diagnostic: dispatch the (idempotent) tile kernel twice.
    structure_loss_tile<<<grid, NTHR, 0, stream>>>(pred, mask);
    structure_loss_tile<<<grid, NTHR, 0, stream>>>(pred, mask);
    structure_loss_final<<<1, 64, 0, stream>>>(out);
}

// Round 7
// 100.951 us; speedup vs baseline: 1.0316x; 1.0316x over previous
//
#include <hip/hip_runtime.h>
#include <math.h>

// StructureLoss: pred [16,2,512,512] f32, mask [16,512,512] f32 -> scalar f32
// loss = mean_b( wbce_b + wiou_b ), weit = 1 + 5*|boxavg31(m) - m|
//
// R12 = R10 (single tile dispatch restored) + LDS b128 vectorization.
// R11's double-dispatch diagnostic: one warm tile = 14.0 us; its dominant
// reducible cost is scalar LDS issue (~6.3 us/CU: 558+192+488 b32 ops/block
// at 5.8 cyc). This round vectorizes all three LDS phases:
//  - P2 vertical: thread=(rowgroup16, f4 colgroup); 46 aligned float4 reads
//    -> 4 column-sums x 16 rows in registers (192 tasks, 138 b128 vs 558 b32)
//  - P3: aligned float4 writes; vsum kept in STAGED-column space (stride 100,
//    cols 0..95 all written) so no +-1 shift breaks alignment anywhere
//  - P4 horizontal: 12 aligned b128 fetch w[0..47]; px jj uses w[jj+1..jj+31]
// All patterns at stride 100 (=4 mod 32 banks) land 8 lanes/4-bank group =
// balanced minimum-cycle b128. Geometry/swizzle/math unchanged from R10.
#define B_   16
#define H_   512
#define W_   512
#define HW_  (H_ * W_)
#define MU_  5.0f
#define KK_INV (1.0f / 961.0f)
#define TH   128
#define TW   64
#define NTHR 512
#define NROWS 158              // TH + 30
#define RSTRIDE 100            // row stride (floats): 16B-aligned, 4 mod 32 banks
#define VSTRIDE 100            // vsum stride == RSTRIDE (staged-col space)
#define NQ 24                  // float4s staged per raw row (96 cols)
#define NSTG (NROWS * NQ)      // 3792 staging tasks
#define NVT2 192               // 8 rowgroups(16) x 24 f4-colgroups
#define NBLK 512               // 8 x 4 x 16

__device__ __align__(16) float g_part[NBLK * 4];

__global__ __launch_bounds__(NTHR, 4) void structure_loss_tile(
    const float* __restrict__ pred,     // [B,2,H,W]
    const float* __restrict__ mask)     // [B,H,W]
{
    __shared__ float smem[NROWS * RSTRIDE];   // 63,200 B; vsum aliases rows 0..127
    __shared__ float wsum[8][4];

    const int tid = threadIdx.x;

    // ---- XCD-aware tile assignment (bijective: 512 = 8 XCDs x 64) ----
    const int bid = (blockIdx.z * gridDim.y + blockIdx.y) * gridDim.x + blockIdx.x;
    const int t   = (bid & 7) * 64 + (bid >> 3);
    const int tx  = t & 7;
    const int ty  = (t >> 3) & 3;
    const int b   = t >> 5;
    const int r0  = ty * TH;
    const int c0  = tx * TW;
    const int blk = t;                  // g_part layout: tile-index order

    const float* mb = mask + (size_t)b * HW_;
    const float* pb = pred + ((size_t)b * 2 + 1) * HW_;   // channel-1 logits

    // ---- Horizontal-phase coordinates: 16 output px per thread ----
    const int r   = tid >> 2;           // 0..127
    const int ch  = tid & 3;            // 0..3
    const int gr  = r0 + r;
    const int gcb = c0 + ch * 16;       // 64B-aligned

    // ---- P1a: pred prefetch (4 float4), issued with the stage loads ----
    const float4* p4 = (const float4*)(pb + gr * W_ + gcb);
    const float4 pq0 = p4[0], pq1 = p4[1], pq2 = p4[2], pq3 = p4[3];

    // ---- P1b: stage raw mask halo: 158 rows x 24 float4 = 3792 tasks ----
    {
        const int gyb = r0 - 15;
        const int gxb = c0 - 16;
        float4 vbuf[8];
        int    laddr[8];
        #pragma unroll
        for (int rnd = 0; rnd < 8; ++rnd) {
            const int task = tid + rnd * NTHR;
            float4 v = make_float4(0.f, 0.f, 0.f, 0.f);
            int la = -1;
            if (task < NSTG) {
                const int row = task / NQ;
                const int q   = task - row * NQ;
                const int gy  = gyb + row;
                const int gx  = gxb + q * 4;    // multiple of 4 -> f4-granular OOB
                if (((unsigned)gy < (unsigned)H_) & ((unsigned)gx < (unsigned)W_))
                    v = *(const float4*)(mb + gy * W_ + gx);
                la = row * RSTRIDE + q * 4;
            }
            vbuf[rnd] = v;
            laddr[rnd] = la;
        }
        #pragma unroll
        for (int rnd = 0; rnd < 8; ++rnd) {
            if (laddr[rnd] >= 0)
                *(float4*)(&smem[laddr[rnd]]) = vbuf[rnd];
        }
    }
    // keep pred values resident (don't let the loads sink past the barriers)
    asm volatile("" :: "v"(pq0.x), "v"(pq0.y), "v"(pq0.z), "v"(pq0.w),
                       "v"(pq1.x), "v"(pq1.y), "v"(pq1.z), "v"(pq1.w),
                       "v"(pq2.x), "v"(pq2.y), "v"(pq2.z), "v"(pq2.w),
                       "v"(pq3.x), "v"(pq3.y), "v"(pq3.z), "v"(pq3.w));
    __syncthreads();

    // ---- P2a: mask row for elementwise (must read raw BEFORE P3 overwrite) ----
    float mv[16];
    {
        const int mbase = (r + 15) * RSTRIDE + ch * 16 + 16;
        #pragma unroll
        for (int k = 0; k < 4; ++k) {
            const int kk = (k + ch) & 3;     // rotation: balanced banks
            const float4 tq = *(const float4*)(&smem[mbase + 4 * kk]);
            mv[kk*4+0] = tq.x; mv[kk*4+1] = tq.y; mv[kk*4+2] = tq.z; mv[kk*4+3] = tq.w;
        }
    }

    // ---- P2b: vertical 31-row sliding sums, 4 columns at once (float4) ----
    // thread = (rg, cg): rows rg*16..rg*16+15, staged cols 4cg..4cg+3
    float4 vs4[16];
    int rg = 0, cg = 0;
    if (tid < NVT2) {
        rg = tid / NQ;                       // 0..7
        cg = tid - rg * NQ;                  // 0..23
        const float* colp = &smem[(rg * 16) * RSTRIDE + 4 * cg];
        float4 s4 = make_float4(0.f, 0.f, 0.f, 0.f);
        #pragma unroll
        for (int d = 0; d < 31; ++d) {
            const float4 v = *(const float4*)(colp + d * RSTRIDE);
            s4.x += v.x; s4.y += v.y; s4.z += v.z; s4.w += v.w;
        }
        vs4[0] = s4;
        #pragma unroll
        for (int i = 1; i < 16; ++i) {
            const float4 a = *(const float4*)(colp + (i + 30) * RSTRIDE);
            const float4 dfl = *(const float4*)(colp + (i - 1) * RSTRIDE);
            s4.x += a.x - dfl.x; s4.y += a.y - dfl.y;
            s4.z += a.z - dfl.z; s4.w += a.w - dfl.w;
            vs4[i] = s4;
        }
    }
    __syncthreads();

    // ---- P3: write vsum [128][100] (staged-col space) over raw rows 0..127 ----
    if (tid < NVT2) {
        float* vout = &smem[(rg * 16) * VSTRIDE + 4 * cg];
        #pragma unroll
        for (int i = 0; i < 16; ++i)
            *(float4*)(vout + i * VSTRIDE) = vs4[i];
    }
    __syncthreads();

    // ---- P4: horizontal 31-tap slide from 12 aligned b128 reads ----
    // w[k] = vsum[r][ch*16 + k]; px jj's window = w[jj+1 .. jj+31]
    float w[48];
    {
        const int base = r * VSTRIDE + ch * 16;   // 16B-aligned
        #pragma unroll
        for (int k = 0; k < 12; ++k) {
            const float4 t4 = *(const float4*)(&smem[base + 4 * k]);
            w[4*k+0] = t4.x; w[4*k+1] = t4.y; w[4*k+2] = t4.z; w[4*k+3] = t4.w;
        }
    }
    float s = 0.0f;
    #pragma unroll
    for (int k = 1; k <= 31; ++k)
        s += w[k];

    float pv[16] = { pq0.x, pq0.y, pq0.z, pq0.w,  pq1.x, pq1.y, pq1.z, pq1.w,
                     pq2.x, pq2.y, pq2.z, pq2.w,  pq3.x, pq3.y, pq3.z, pq3.w };

    float s_w = 0.0f, s_wb = 0.0f, s_in = 0.0f, s_un = 0.0f;
    #pragma unroll
    for (int j = 0; j < 16; ++j) {
        const float avg = s * KK_INV;
        const float m = mv[j];
        const float p = pv[j];

        const float weit = 1.0f + MU_ * fabsf(avg - m);
        // e = exp(-|p|); bce = max(p,0) - p*m + log(1+e); sigmoid = (p>=0?1:e)/(1+e)
        const float e    = __expf(-fabsf(p));
        const float inv  = __builtin_amdgcn_rcpf(1.0f + e);
        const float bce  = fmaxf(p, 0.0f) - p * m + __logf(1.0f + e);
        const float ps   = (p >= 0.0f ? 1.0f : e) * inv;

        s_w  += weit;
        s_wb += weit * bce;
        s_in += ps * m * weit;
        s_un += (ps + m) * weit;

        if (j < 15)
            s += w[j + 32] - w[j + 1];
    }

    // ---- block reduction: wave shuffle -> LDS -> one store per component ----
    const int lane = tid & 63;
    const int wid  = tid >> 6;          // 0..7
    float vals[4] = { s_w, s_wb, s_in, s_un };
    #pragma unroll
    for (int q = 0; q < 4; ++q) {
        float v = vals[q];
        #pragma unroll
        for (int off = 32; off > 0; off >>= 1)
            v += __shfl_down(v, off);
        if (lane == 0) wsum[wid][q] = v;
    }
    __syncthreads();
    if (tid < 4) {
        float tot = 0.0f;
        #pragma unroll
        for (int wv = 0; wv < 8; ++wv) tot += wsum[wv][tid];
        g_part[blk * 4 + tid] = tot;    // unconditional write -> no memset needed
    }
}

__global__ void structure_loss_final(float* __restrict__ out)
{
    // 64 threads; 4 threads per batch (32 blocks/batch), 8 float4 each.
    const int t = threadIdx.x;
    const float4* p4 = (const float4*)g_part;    // one float4 per block
    float4 v = make_float4(0.f, 0.f, 0.f, 0.f);
    #pragma unroll
    for (int j = 0; j < 8; ++j) {
        const float4 q = p4[t * 8 + j];
        v.x += q.x; v.y += q.y; v.z += q.z; v.w += q.w;
    }
    #pragma unroll
    for (int off = 2; off > 0; off >>= 1) {
        v.x += __shfl_down(v.x, off);
        v.y += __shfl_down(v.y, off);
        v.z += __shfl_down(v.z, off);
        v.w += __shfl_down(v.w, off);
    }
    float loss = 0.0f;
    if ((t & 3) == 0) {
        const float sw = v.x, swb = v.y, inter = v.z, uni = v.w;
        loss = swb / sw + 1.0f - (inter + 1.0f) / (uni - inter + 1.0f);
    }
    #pragma unroll
    for (int off = 32; off >= 4; off >>= 1)
        loss += __shfl_down(loss, off);
    if (t == 0) out[0] = loss * (1.0f / (float)B_);
}

extern "C" void kernel_launch(void* const* d_in, const int* in_sizes, int n_in,
                              void* d_out, int out_size, void* d_ws, size_t ws_size,
                              hipStream_t stream) {
    const float* pred = (const float*)d_in[0];
    const float* mask = (const float*)d_in[1];
    float* out = (float*)d_out;
    (void)d_ws; (void)ws_size;          // workspace deliberately untouched

    dim3 grid(W_ / TW, H_ / TH, B_);    // 8 x 4 x 16 = 512 blocks
    structure_loss_tile<<<grid, NTHR, 0, stream>>>(pred, mask);
    structure_loss_final<<<1, 64, 0, stream>>>(out);
}

// Round 8
// 91.876 us; speedup vs baseline: 1.1335x; 1.0988x over previous
//
#include <hip/hip_runtime.h>
#include <math.h>

// StructureLoss: pred [16,2,512,512] f32, mask [16,512,512] f32 -> scalar f32
// loss = mean_b( wbce_b + wiou_b ), weit = 1 + 5*|boxavg31(m) - m|
//
// R13 = exact revert to R10, the best-measured variant (90.15 us).
// R12's LDS b128 vectorization was a ~4.5 us regression after clock
// normalization (vs4[16]=64 VGPRs live across a barrier + w[48] in P4
// likely crossed the 128-VGPR __launch_bounds__ cliff -> spills).
// R10's verified composition:
//  - 128x64 tiles, 512 thr, 512 blocks = 2/CU x 1 round
//  - batched float4 halo staging (8 loads in flight; defeats the VGPR-
//    minimizer serialization seen in R7's 54 us fused kernel)
//  - RSTRIDE=100: row stride = 4 mod 32 banks -> the fixed-column mv
//    re-read is 2-way (free); 96 was a 16-way conflict
//  - bijective XCD swizzle: each XCD owns 64 consecutive tiles = 2 whole
//    batches -> all halo re-reads are private-L2 hits (1 MB << 4 MiB)
//  - vertical 62-row windows -> 32 outputs/task, vsum aliased over the
//    staged tile ([128][95], odd stride), 16 px/thread horizontal phase
//  - two-kernel finish, partials in __device__ global (d_ws untouched;
//    the harness's 256 MiB ws poison fill runs unconditionally anyway)
// Ledger for the record: fixed harness overhead ~70 us/iter (42 us poison
// fill + ~28 us restore memsets/gaps); controllable ~20 us of which tile
// ~14-16 (measured via R11 double-dispatch) vs ~10-12 us cold-HBM floor.
#define B_   16
#define H_   512
#define W_   512
#define HW_  (H_ * W_)
#define MU_  5.0f
#define KK_INV (1.0f / 961.0f)
#define TH   128
#define TW   64
#define NTHR 512
#define NROWS 158              // TH + 30
#define RSTRIDE 100            // raw row stride: 16B-aligned, 4 mod 32 banks
#define VSTRIDE 95             // vsum stride: odd -> scalar reads <=2-way
#define NQ 24                  // float4s staged per raw row (96 cols, 94 used)
#define NSTG (NROWS * NQ)      // 3792 staging tasks
#define NVTASK 376             // 4 row-groups(32) x 94 halo cols
#define NBLK 512               // 8 x 4 x 16

__device__ __align__(16) float g_part[NBLK * 4];

__global__ __launch_bounds__(NTHR, 4) void structure_loss_tile(
    const float* __restrict__ pred,     // [B,2,H,W]
    const float* __restrict__ mask)     // [B,H,W]
{
    __shared__ float smem[NROWS * RSTRIDE];   // 63,200 B; vsum aliased after P3
    __shared__ float wsum[8][4];

    const int tid = threadIdx.x;

    // ---- XCD-aware tile assignment (bijective: 512 = 8 XCDs x 64) ----
    const int bid = (blockIdx.z * gridDim.y + blockIdx.y) * gridDim.x + blockIdx.x;
    const int t   = (bid & 7) * 64 + (bid >> 3);
    const int tx  = t & 7;
    const int ty  = (t >> 3) & 3;
    const int b   = t >> 5;
    const int r0  = ty * TH;
    const int c0  = tx * TW;
    const int blk = t;                  // g_part layout: tile-index order

    const float* mb = mask + (size_t)b * HW_;
    const float* pb = pred + ((size_t)b * 2 + 1) * HW_;   // channel-1 logits

    // ---- Horizontal-phase coordinates: 16 output px per thread ----
    const int r   = tid >> 2;           // 0..127
    const int ch  = tid & 3;            // 0..3
    const int gr  = r0 + r;
    const int gcb = c0 + ch * 16;       // 64B-aligned

    // ---- P1a: pred prefetch (4 float4), issued with the stage loads ----
    const float4* p4 = (const float4*)(pb + gr * W_ + gcb);
    const float4 pq0 = p4[0], pq1 = p4[1], pq2 = p4[2], pq3 = p4[3];

    // ---- P1b: stage raw mask halo: 158 rows x 24 float4 = 3792 tasks ----
    {
        const int gyb = r0 - 15;
        const int gxb = c0 - 16;
        float4 vbuf[8];
        int    laddr[8];
        #pragma unroll
        for (int rnd = 0; rnd < 8; ++rnd) {
            const int task = tid + rnd * NTHR;
            float4 v = make_float4(0.f, 0.f, 0.f, 0.f);
            int la = -1;
            if (task < NSTG) {
                const int row = task / NQ;
                const int q   = task - row * NQ;
                const int gy  = gyb + row;
                const int gx  = gxb + q * 4;    // multiple of 4 -> f4-granular OOB
                if (((unsigned)gy < (unsigned)H_) & ((unsigned)gx < (unsigned)W_))
                    v = *(const float4*)(mb + gy * W_ + gx);
                la = row * RSTRIDE + q * 4;
            }
            vbuf[rnd] = v;
            laddr[rnd] = la;
        }
        #pragma unroll
        for (int rnd = 0; rnd < 8; ++rnd) {
            if (laddr[rnd] >= 0)
                *(float4*)(&smem[laddr[rnd]]) = vbuf[rnd];
        }
    }
    // keep pred values resident (don't let the loads sink past the barriers)
    asm volatile("" :: "v"(pq0.x), "v"(pq0.y), "v"(pq0.z), "v"(pq0.w),
                       "v"(pq1.x), "v"(pq1.y), "v"(pq1.z), "v"(pq1.w),
                       "v"(pq2.x), "v"(pq2.y), "v"(pq2.z), "v"(pq2.w),
                       "v"(pq3.x), "v"(pq3.y), "v"(pq3.z), "v"(pq3.w));
    __syncthreads();

    // ---- P2: mask row for elementwise (from staged raw) + vertical sums ----
    float mv[16];
    {
        const int mbase = (r + 15) * RSTRIDE + ch * 16 + 16;
        #pragma unroll
        for (int k = 0; k < 4; ++k) {
            const int kk = (k + ch) & 3;     // rotation: 2-way (free) with RSTRIDE=100
            const float4 tq = *(const float4*)(&smem[mbase + 4 * kk]);
            mv[kk*4+0] = tq.x; mv[kk*4+1] = tq.y; mv[kk*4+2] = tq.z; mv[kk*4+3] = tq.w;
        }
    }

    float vs[32];
    int rg = 0, cc = 0;
    if (tid < NVTASK) {
        rg = tid / 94;                       // 0..3
        cc = tid - rg * 94;                  // 0..93
        const float* col = &smem[(rg * 32) * RSTRIDE + cc + 1];
        float s = 0.0f;
        #pragma unroll
        for (int d = 0; d < 31; ++d)
            s += col[d * RSTRIDE];
        vs[0] = s;
        #pragma unroll
        for (int i = 1; i < 32; ++i) {
            s += col[(i + 30) * RSTRIDE] - col[(i - 1) * RSTRIDE];
            vs[i] = s;
        }
    }
    __syncthreads();

    // ---- P3: write vsum [128][95] over the raw region (alias, post-barrier) ----
    if (tid < NVTASK) {
        float* vout = &smem[(rg * 32) * VSTRIDE + cc];
        #pragma unroll
        for (int i = 0; i < 32; ++i)
            vout[i * VSTRIDE] = vs[i];
    }
    __syncthreads();

    // ---- P4: horizontal 31-tap slide fused with elementwise math ----
    const int base = r * VSTRIDE + ch * 16;
    float s = 0.0f;
    #pragma unroll
    for (int d = 0; d < 31; ++d)
        s += smem[base + d];

    float pv[16] = { pq0.x, pq0.y, pq0.z, pq0.w,  pq1.x, pq1.y, pq1.z, pq1.w,
                     pq2.x, pq2.y, pq2.z, pq2.w,  pq3.x, pq3.y, pq3.z, pq3.w };

    float s_w = 0.0f, s_wb = 0.0f, s_in = 0.0f, s_un = 0.0f;
    #pragma unroll
    for (int j = 0; j < 16; ++j) {
        const float avg = s * KK_INV;
        const float m = mv[j];
        const float p = pv[j];

        const float weit = 1.0f + MU_ * fabsf(avg - m);
        // e = exp(-|p|); bce = max(p,0) - p*m + log(1+e); sigmoid = (p>=0?1:e)/(1+e)
        const float e    = __expf(-fabsf(p));
        const float inv  = __builtin_amdgcn_rcpf(1.0f + e);
        const float bce  = fmaxf(p, 0.0f) - p * m + __logf(1.0f + e);
        const float ps   = (p >= 0.0f ? 1.0f : e) * inv;

        s_w  += weit;
        s_wb += weit * bce;
        s_in += ps * m * weit;
        s_un += (ps + m) * weit;

        if (j < 15)
            s += smem[base + 31 + j] - smem[base + j];
    }

    // ---- block reduction: wave shuffle -> LDS -> one store per component ----
    const int lane = tid & 63;
    const int wid  = tid >> 6;          // 0..7
    float vals[4] = { s_w, s_wb, s_in, s_un };
    #pragma unroll
    for (int q = 0; q < 4; ++q) {
        float v = vals[q];
        #pragma unroll
        for (int off = 32; off > 0; off >>= 1)
            v += __shfl_down(v, off);
        if (lane == 0) wsum[wid][q] = v;
    }
    __syncthreads();
    if (tid < 4) {
        float tot = 0.0f;
        #pragma unroll
        for (int w = 0; w < 8; ++w) tot += wsum[w][tid];
        g_part[blk * 4 + tid] = tot;    // unconditional write -> no memset needed
    }
}

__global__ void structure_loss_final(float* __restrict__ out)
{
    // 64 threads; 4 threads per batch (32 blocks/batch), 8 float4 each.
    const int t = threadIdx.x;
    const float4* p4 = (const float4*)g_part;    // one float4 per block
    float4 v = make_float4(0.f, 0.f, 0.f, 0.f);
    #pragma unroll
    for (int j = 0; j < 8; ++j) {
        const float4 q = p4[t * 8 + j];
        v.x += q.x; v.y += q.y; v.z += q.z; v.w += q.w;
    }
    #pragma unroll
    for (int off = 2; off > 0; off >>= 1) {
        v.x += __shfl_down(v.x, off);
        v.y += __shfl_down(v.y, off);
        v.z += __shfl_down(v.z, off);
        v.w += __shfl_down(v.w, off);
    }
    float loss = 0.0f;
    if ((t & 3) == 0) {
        const float sw = v.x, swb = v.y, inter = v.z, uni = v.w;
        loss = swb / sw + 1.0f - (inter + 1.0f) / (uni - inter + 1.0f);
    }
    #pragma unroll
    for (int off = 32; off >= 4; off >>= 1)
        loss += __shfl_down(loss, off);
    if (t == 0) out[0] = loss * (1.0f / (float)B_);
}

extern "C" void kernel_launch(void* const* d_in, const int* in_sizes, int n_in,
                              void* d_out, int out_size, void* d_ws, size_t ws_size,
                              hipStream_t stream) {
    const float* pred = (const float*)d_in[0];
    const float* mask = (const float*)d_in[1];
    float* out = (float*)d_out;
    (void)d_ws; (void)ws_size;          // workspace deliberately untouched

    dim3 grid(W_ / TW, H_ / TH, B_);    // 8 x 4 x 16 = 512 blocks
    structure_loss_tile<<<grid, NTHR, 0, stream>>>(pred, mask);
    structure_loss_final<<<1, 64, 0, stream>>>(out);
}